// Round 1
// baseline (100.174 us; speedup 1.0000x reference)
//
#include <hip/hip_runtime.h>
#include <hip/hip_bf16.h>
#include <cstdint>
#include <cstddef>

#define BB 32
#define SS 4096
#define DD 256
#define UU 256

typedef __attribute__((ext_vector_type(8))) short short8;
typedef __attribute__((ext_vector_type(4))) float f32x4;

struct __align__(8)  us4 { unsigned short x, y, z, w; };
struct __align__(16) ui4 { unsigned int a, b, c, d; };

__device__ __forceinline__ unsigned short f2bf(float x) {
  union { float f; unsigned int u; } c; c.f = x;
  unsigned int r = c.u + 0x7FFFu + ((c.u >> 16) & 1u);
  return (unsigned short)(r >> 16);
}

// K1: posb[b][u] = position[b] @ W1[:,u] + b1[u] + b2[u]   (exact fp32)
__global__ void k_posproj(const float* __restrict__ pos, const float* __restrict__ W1,
                          const float* __restrict__ b1, const float* __restrict__ b2,
                          float* __restrict__ posb) {
  __shared__ float p[DD];
  int b = blockIdx.x, u = threadIdx.x;
  p[u] = pos[b * DD + u];
  __syncthreads();
  float acc = b1[u] + b2[u];
#pragma unroll 4
  for (int d = 0; d < DD; ++d) acc = fmaf(p[d], W1[(size_t)d * UU + u], acc);
  posb[b * UU + u] = acc;
}

// K1b: w2t[u][d] = bf16(W2[d][u])  (tiled transpose)
__global__ void k_w2t(const float* __restrict__ W2, unsigned short* __restrict__ w2t) {
  __shared__ unsigned short tile[16][17];
  int di = blockIdx.x * 16, ui = blockIdx.y * 16;
  int t = threadIdx.x;
  int r = t >> 4, c = t & 15;
  tile[c][r] = f2bf(W2[(size_t)(di + r) * UU + ui + c]);
  __syncthreads();
  w2t[(size_t)(ui + r) * DD + di + c] = tile[r][c];
}

// K2: scores[b][s] = sum_u tanh(posb[b][u] + options[b][s]@W2[:,u]) * V[u] + bv
// 64-row x 256-u tile per block, 4 waves (2x2), mfma 16x16x32 bf16.
#define PITCH 72
__global__ __launch_bounds__(256) void k_score(
    const float* __restrict__ options, const unsigned short* __restrict__ w2t,
    const float* __restrict__ posb, const float* __restrict__ V,
    const float* __restrict__ bvp, float* __restrict__ scores) {
  __shared__ __align__(16) unsigned short aT[64][PITCH];   // options tile [row][k]
  __shared__ __align__(16) unsigned short bT[UU][PITCH];   // W2^T chunk  [u][k]
  __shared__ float posv_l[UU];
  __shared__ float vv_l[UU];
  __shared__ float red[64][2];

  const int tid = threadIdx.x;
  const int b  = blockIdx.y;
  const int s0 = blockIdx.x * 64;
  const int wid = tid >> 6, l = tid & 63;
  const int wr = wid >> 1, wc = wid & 1;
  const int il = l & 15, kg = l >> 4;

  posv_l[tid] = posb[b * UU + tid];
  vv_l[tid]   = V[tid];

  const float* optb = options + ((size_t)b * SS + s0) * DD;

  f32x4 acc[2][8];
#pragma unroll
  for (int mi = 0; mi < 2; ++mi)
#pragma unroll
    for (int ni = 0; ni < 8; ++ni) {
      f32x4 z = {0.f, 0.f, 0.f, 0.f};
      acc[mi][ni] = z;
    }

  for (int kc0 = 0; kc0 < DD; kc0 += 64) {
    // stage A: 64 rows x 64 k (f32 -> bf16)
#pragma unroll
    for (int i = 0; i < 4; ++i) {
      int j  = i * 256 + tid;        // float4 index 0..1023
      int r  = j >> 4;
      int k4 = (j & 15) << 2;
      const float4 f = *(const float4*)(optb + (size_t)r * DD + kc0 + k4);
      us4 h; h.x = f2bf(f.x); h.y = f2bf(f.y); h.z = f2bf(f.z); h.w = f2bf(f.w);
      *(us4*)&aT[r][k4] = h;
    }
    // stage B: 256 u x 64 k (already bf16, contiguous k)
    {
      const ui4* src = (const ui4*)(w2t + (size_t)tid * DD + kc0);
#pragma unroll
      for (int i = 0; i < 8; ++i) *(ui4*)&bT[tid][i * 8] = src[i];
    }
    __syncthreads();

#pragma unroll
    for (int kc = 0; kc < 2; ++kc) {
      const int ko = kc * 32 + kg * 8;
      short8 a0 = *(const short8*)&aT[wr * 32 + il][ko];
      short8 a1 = *(const short8*)&aT[wr * 32 + 16 + il][ko];
#pragma unroll
      for (int ni = 0; ni < 8; ++ni) {
        short8 bv = *(const short8*)&bT[wc * 128 + ni * 16 + il][ko];
        acc[0][ni] = __builtin_amdgcn_mfma_f32_16x16x32_bf16(a0, bv, acc[0][ni], 0, 0, 0);
        acc[1][ni] = __builtin_amdgcn_mfma_f32_16x16x32_bf16(a1, bv, acc[1][ni], 0, 0, 0);
      }
    }
    __syncthreads();
  }

  // epilogue: tanh(acc + posb) * V, reduce over u
  float part[2][4];
#pragma unroll
  for (int mi = 0; mi < 2; ++mi)
#pragma unroll
    for (int r = 0; r < 4; ++r) part[mi][r] = 0.f;

#pragma unroll
  for (int ni = 0; ni < 8; ++ni) {
    int u = wc * 128 + ni * 16 + il;
    float pv = posv_l[u], vv = vv_l[u];
#pragma unroll
    for (int mi = 0; mi < 2; ++mi)
#pragma unroll
      for (int r = 0; r < 4; ++r) {
        float x = acc[mi][ni][r] + pv;
        float t = 1.f - __fdividef(2.f, __expf(2.f * x) + 1.f);
        part[mi][r] = fmaf(t, vv, part[mi][r]);
      }
  }
#pragma unroll
  for (int mi = 0; mi < 2; ++mi)
#pragma unroll
    for (int r = 0; r < 4; ++r) {
      float p = part[mi][r];
      p += __shfl_xor(p, 1);
      p += __shfl_xor(p, 2);
      p += __shfl_xor(p, 4);
      p += __shfl_xor(p, 8);
      part[mi][r] = p;
    }
  if (il == 0) {
#pragma unroll
    for (int mi = 0; mi < 2; ++mi)
#pragma unroll
      for (int r = 0; r < 4; ++r)
        red[wr * 32 + mi * 16 + kg * 4 + r][wc] = part[mi][r];
  }
  __syncthreads();
  if (tid < 64)
    scores[(size_t)b * SS + s0 + tid] = red[tid][0] + red[tid][1] + bvp[0];
}

// K3: softmax over S per batch; writes normalized weights to output
__global__ __launch_bounds__(1024) void k_softmax(const float* __restrict__ scores,
                                                  float* __restrict__ wgt) {
  __shared__ float sred[16];
  int b = blockIdx.x, t = threadIdx.x;
  int lane = t & 63, wv = t >> 6;
  const float* sb = scores + (size_t)b * SS;
  float v0 = sb[t], v1 = sb[t + 1024], v2 = sb[t + 2048], v3 = sb[t + 3072];
  float m = fmaxf(fmaxf(v0, v1), fmaxf(v2, v3));
#pragma unroll
  for (int off = 32; off >= 1; off >>= 1) m = fmaxf(m, __shfl_xor(m, off));
  if (lane == 0) sred[wv] = m;
  __syncthreads();
  float gm = sred[0];
#pragma unroll
  for (int i = 1; i < 16; ++i) gm = fmaxf(gm, sred[i]);
  __syncthreads();
  float e0 = __expf(v0 - gm), e1 = __expf(v1 - gm);
  float e2 = __expf(v2 - gm), e3 = __expf(v3 - gm);
  float s = e0 + e1 + e2 + e3;
#pragma unroll
  for (int off = 32; off >= 1; off >>= 1) s += __shfl_xor(s, off);
  if (lane == 0) sred[wv] = s;
  __syncthreads();
  float gs = 0.f;
#pragma unroll
  for (int i = 0; i < 16; ++i) gs += sred[i];
  float inv = 1.f / gs;
  float* wb = wgt + (size_t)b * SS;
  wb[t] = e0 * inv; wb[t + 1024] = e1 * inv;
  wb[t + 2048] = e2 * inv; wb[t + 3072] = e3 * inv;
}

// K4: partial context sums over 64-row chunks (fp32 options, fp32 weights)
__global__ __launch_bounds__(256) void k_ctx_part(const float* __restrict__ options,
                                                  const float* __restrict__ wgt,
                                                  float* __restrict__ part) {
  __shared__ float wl[64];
  __shared__ float4 pr[256];
  int ch = blockIdx.x, b = blockIdx.y, t = threadIdx.x;
  if (t < 64) wl[t] = wgt[(size_t)b * SS + ch * 64 + t];
  __syncthreads();
  int rg = t >> 6;
  int d4 = (t & 63) << 2;
  float a0 = 0.f, a1 = 0.f, a2 = 0.f, a3 = 0.f;
  const float* base = options + ((size_t)b * SS + (size_t)ch * 64) * DD;
#pragma unroll 4
  for (int i = 0; i < 16; ++i) {
    int s = i * 4 + rg;
    const float4 o = *(const float4*)(base + (size_t)s * DD + d4);
    float w = wl[s];
    a0 = fmaf(w, o.x, a0); a1 = fmaf(w, o.y, a1);
    a2 = fmaf(w, o.z, a2); a3 = fmaf(w, o.w, a3);
  }
  pr[t] = make_float4(a0, a1, a2, a3);
  __syncthreads();
  if (t < 64) {
    float4 v0 = pr[t], v1 = pr[64 + t], v2 = pr[128 + t], v3 = pr[192 + t];
    float4 o;
    o.x = v0.x + v1.x + v2.x + v3.x;
    o.y = v0.y + v1.y + v2.y + v3.y;
    o.z = v0.z + v1.z + v2.z + v3.z;
    o.w = v0.w + v1.w + v2.w + v3.w;
    *(float4*)&part[(((size_t)b * 64 + ch) * DD) + d4] = o;
  }
}

// K5: reduce 64 chunk partials -> context
__global__ void k_ctx_final(const float* __restrict__ part, float* __restrict__ ctx) {
  int b = blockIdx.x, d = threadIdx.x;
  float s = 0.f;
#pragma unroll 4
  for (int ch = 0; ch < 64; ++ch) s += part[((size_t)b * 64 + ch) * DD + d];
  ctx[b * DD + d] = s;
}

extern "C" void kernel_launch(void* const* d_in, const int* in_sizes, int n_in,
                              void* d_out, int out_size, void* d_ws, size_t ws_size,
                              hipStream_t stream) {
  const float* position = (const float*)d_in[0];
  const float* options  = (const float*)d_in[1];
  const float* W1 = (const float*)d_in[2];
  const float* b1 = (const float*)d_in[3];
  const float* W2 = (const float*)d_in[4];
  const float* b2 = (const float*)d_in[5];
  const float* V  = (const float*)d_in[6];
  const float* bv = (const float*)d_in[7];

  float* out = (float*)d_out;
  float* ctx_out = out;              // [32,256]
  float* wgt_out = out + BB * DD;    // [32,4096]

  char* ws = (char*)d_ws;
  float* posb            = (float*)ws;                                      // 32 KB
  unsigned short* w2t    = (unsigned short*)(ws + 32 * 1024);               // 128 KB
  float* scores          = (float*)(ws + 160 * 1024);                       // 512 KB
  float* part            = (float*)(ws + 672 * 1024);                       // 2 MB

  k_posproj<<<BB, 256, 0, stream>>>(position, W1, b1, b2, posb);
  k_w2t<<<dim3(16, 16), 256, 0, stream>>>(W2, w2t);
  k_score<<<dim3(SS / 64, BB), 256, 0, stream>>>(options, w2t, posb, V, bv, scores);
  k_softmax<<<BB, 1024, 0, stream>>>(scores, wgt_out);
  k_ctx_part<<<dim3(64, BB), 256, 0, stream>>>(options, wgt_out, part);
  k_ctx_final<<<BB, DD, 0, stream>>>(part, ctx_out);
}

// Round 2
// 97.732 us; speedup vs baseline: 1.0250x; 1.0250x over previous
//
#include <hip/hip_runtime.h>
#include <hip/hip_bf16.h>
#include <cstdint>
#include <cstddef>

#define BB 32
#define SS 4096
#define DD 256
#define UU 256

typedef __attribute__((ext_vector_type(8))) short short8;
typedef __attribute__((ext_vector_type(4))) float f32x4;

struct __align__(8)  us4 { unsigned short x, y, z, w; };
struct __align__(16) ui4 { unsigned int a, b, c, d; };

__device__ __forceinline__ unsigned short f2bf(float x) {
  union { float f; unsigned int u; } c; c.f = x;
  unsigned int r = c.u + 0x7FFFu + ((c.u >> 16) & 1u);
  return (unsigned short)(r >> 16);
}

// K1: posb[b][u] = position[b] @ W1[:,u] + b1[u] + b2[u]   (exact fp32)
__global__ void k_posproj(const float* __restrict__ pos, const float* __restrict__ W1,
                          const float* __restrict__ b1, const float* __restrict__ b2,
                          float* __restrict__ posb) {
  __shared__ float p[DD];
  int b = blockIdx.x, u = threadIdx.x;
  p[u] = pos[b * DD + u];
  __syncthreads();
  float acc = b1[u] + b2[u];
#pragma unroll 4
  for (int d = 0; d < DD; ++d) acc = fmaf(p[d], W1[(size_t)d * UU + u], acc);
  posb[b * UU + u] = acc;
}

// K1b: w2t[u][d] = bf16(W2[d][u])  (tiled transpose)
__global__ void k_w2t(const float* __restrict__ W2, unsigned short* __restrict__ w2t) {
  __shared__ unsigned short tile[16][17];
  int di = blockIdx.x * 16, ui = blockIdx.y * 16;
  int t = threadIdx.x;
  int r = t >> 4, c = t & 15;
  tile[c][r] = f2bf(W2[(size_t)(di + r) * UU + ui + c]);
  __syncthreads();
  w2t[(size_t)(ui + r) * DD + di + c] = tile[r][c];
}

// K2 (fused): per 64-row chunk:
//   score[s] = sum_u tanh(posb[u] + opt[s]@W2[:,u]) * V[u] + bv
//   m = max_s score, p_s = exp(score_s - m), l = sum p
//   part_ctx[d] = sum_s p_s * opt[s][d]   (fp32 re-read, L2/L3-hot)
// writes: scores (ws), part_ctx (ws), (m,l) (ws)
#define PITCH 72
__global__ __launch_bounds__(256) void k_score_ctx(
    const float* __restrict__ options, const unsigned short* __restrict__ w2t,
    const float* __restrict__ posb, const float* __restrict__ V,
    const float* __restrict__ bvp, float* __restrict__ scores,
    float* __restrict__ part, float2* __restrict__ ml) {
  __shared__ __align__(16) unsigned short aT[64][PITCH];   // options tile [row][k]
  __shared__ __align__(16) unsigned short bT[UU][PITCH];   // W2^T chunk  [u][k]
  __shared__ float posv_l[UU];
  __shared__ float vv_l[UU];
  __shared__ float red[64][2];
  __shared__ float pbuf[64];
  __shared__ float mlb[2];
  __shared__ float4 pr[256];

  const int tid = threadIdx.x;
  const int ch = blockIdx.x;
  const int b  = blockIdx.y;
  const int s0 = ch * 64;
  const int wid = tid >> 6, l = tid & 63;
  const int wr = wid >> 1, wc = wid & 1;
  const int il = l & 15, kg = l >> 4;

  posv_l[tid] = posb[b * UU + tid];
  vv_l[tid]   = V[tid];

  const float* optb = options + ((size_t)b * SS + s0) * DD;

  f32x4 acc[2][8];
#pragma unroll
  for (int mi = 0; mi < 2; ++mi)
#pragma unroll
    for (int ni = 0; ni < 8; ++ni) {
      f32x4 z = {0.f, 0.f, 0.f, 0.f};
      acc[mi][ni] = z;
    }

  for (int kc0 = 0; kc0 < DD; kc0 += 64) {
    // stage A: 64 rows x 64 k (f32 -> bf16)
#pragma unroll
    for (int i = 0; i < 4; ++i) {
      int j  = i * 256 + tid;        // float4 index 0..1023
      int r  = j >> 4;
      int k4 = (j & 15) << 2;
      const float4 f = *(const float4*)(optb + (size_t)r * DD + kc0 + k4);
      us4 h; h.x = f2bf(f.x); h.y = f2bf(f.y); h.z = f2bf(f.z); h.w = f2bf(f.w);
      *(us4*)&aT[r][k4] = h;
    }
    // stage B: 256 u x 64 k (already bf16, contiguous k)
    {
      const ui4* src = (const ui4*)(w2t + (size_t)tid * DD + kc0);
#pragma unroll
      for (int i = 0; i < 8; ++i) *(ui4*)&bT[tid][i * 8] = src[i];
    }
    __syncthreads();

#pragma unroll
    for (int kc = 0; kc < 2; ++kc) {
      const int ko = kc * 32 + kg * 8;
      short8 a0 = *(const short8*)&aT[wr * 32 + il][ko];
      short8 a1 = *(const short8*)&aT[wr * 32 + 16 + il][ko];
#pragma unroll
      for (int ni = 0; ni < 8; ++ni) {
        short8 bvf = *(const short8*)&bT[wc * 128 + ni * 16 + il][ko];
        acc[0][ni] = __builtin_amdgcn_mfma_f32_16x16x32_bf16(a0, bvf, acc[0][ni], 0, 0, 0);
        acc[1][ni] = __builtin_amdgcn_mfma_f32_16x16x32_bf16(a1, bvf, acc[1][ni], 0, 0, 0);
      }
    }
    __syncthreads();
  }

  // epilogue: tanh(acc + posb) * V, reduce over u
  float part_r[2][4];
#pragma unroll
  for (int mi = 0; mi < 2; ++mi)
#pragma unroll
    for (int r = 0; r < 4; ++r) part_r[mi][r] = 0.f;

#pragma unroll
  for (int ni = 0; ni < 8; ++ni) {
    int u = wc * 128 + ni * 16 + il;
    float pv = posv_l[u], vv = vv_l[u];
#pragma unroll
    for (int mi = 0; mi < 2; ++mi)
#pragma unroll
      for (int r = 0; r < 4; ++r) {
        float x = acc[mi][ni][r] + pv;
        float t = 1.f - __fdividef(2.f, __expf(2.f * x) + 1.f);
        part_r[mi][r] = fmaf(t, vv, part_r[mi][r]);
      }
  }
#pragma unroll
  for (int mi = 0; mi < 2; ++mi)
#pragma unroll
    for (int r = 0; r < 4; ++r) {
      float p = part_r[mi][r];
      p += __shfl_xor(p, 1);
      p += __shfl_xor(p, 2);
      p += __shfl_xor(p, 4);
      p += __shfl_xor(p, 8);
      part_r[mi][r] = p;
    }
  if (il == 0) {
#pragma unroll
    for (int mi = 0; mi < 2; ++mi)
#pragma unroll
      for (int r = 0; r < 4; ++r)
        red[wr * 32 + mi * 16 + kg * 4 + r][wc] = part_r[mi][r];
  }
  __syncthreads();

  // local softmax stats over the 64 rows (wave 0)
  const float bvv = bvp[0];
  if (tid < 64) {
    float sv = red[tid][0] + red[tid][1] + bvv;
    scores[(size_t)b * SS + s0 + tid] = sv;
    float m = sv;
#pragma unroll
    for (int off = 32; off >= 1; off >>= 1) m = fmaxf(m, __shfl_xor(m, off));
    float p = __expf(sv - m);
    float ls = p;
#pragma unroll
    for (int off = 32; off >= 1; off >>= 1) ls += __shfl_xor(ls, off);
    pbuf[tid] = p;
    if (tid == 0) { mlb[0] = m; mlb[1] = ls; }
  }
  __syncthreads();

  // partial context: fp32 re-read of the tile (L2/L3-hot)
  {
    int rg = tid >> 6;
    int d4 = (tid & 63) << 2;
    float a0 = 0.f, a1 = 0.f, a2 = 0.f, a3 = 0.f;
#pragma unroll 4
    for (int i = 0; i < 16; ++i) {
      int s = i * 4 + rg;
      const float4 o = *(const float4*)(optb + (size_t)s * DD + d4);
      float w = pbuf[s];
      a0 = fmaf(w, o.x, a0); a1 = fmaf(w, o.y, a1);
      a2 = fmaf(w, o.z, a2); a3 = fmaf(w, o.w, a3);
    }
    pr[tid] = make_float4(a0, a1, a2, a3);
  }
  __syncthreads();
  if (tid < 64) {
    int d4 = tid << 2;
    float4 v0 = pr[tid], v1 = pr[64 + tid], v2 = pr[128 + tid], v3 = pr[192 + tid];
    float4 o;
    o.x = v0.x + v1.x + v2.x + v3.x;
    o.y = v0.y + v1.y + v2.y + v3.y;
    o.z = v0.z + v1.z + v2.z + v3.z;
    o.w = v0.w + v1.w + v2.w + v3.w;
    *(float4*)&part[(((size_t)b * 64 + ch) * DD) + d4] = o;
  }
  if (tid == 0) ml[b * 64 + ch] = make_float2(mlb[0], mlb[1]);
}

// K3: per batch — combine 64 chunk partials, emit context + weights
__global__ __launch_bounds__(256) void k_final(
    const float* __restrict__ scores, const float* __restrict__ part,
    const float2* __restrict__ ml, float* __restrict__ ctx,
    float* __restrict__ wgt) {
  __shared__ float ms[64], lsh[64];
  int b = blockIdx.x, t = threadIdx.x;
  if (t < 64) { float2 v = ml[b * 64 + t]; ms[t] = v.x; lsh[t] = v.y; }
  __syncthreads();
  float gm = ms[0];
#pragma unroll
  for (int i = 1; i < 64; ++i) gm = fmaxf(gm, ms[i]);
  float gs = 0.f;
#pragma unroll
  for (int i = 0; i < 64; ++i) gs += lsh[i] * __expf(ms[i] - gm);
  float inv = 1.f / gs;
  // context: d = t
  float acc = 0.f;
#pragma unroll 4
  for (int i = 0; i < 64; ++i)
    acc += part[((size_t)b * 64 + i) * DD + t] * __expf(ms[i] - gm);
  ctx[b * DD + t] = acc * inv;
  // weights
  const float* sb = scores + (size_t)b * SS;
  float* wb = wgt + (size_t)b * SS;
#pragma unroll 4
  for (int i = 0; i < 16; ++i) {
    int s = i * 256 + t;
    wb[s] = __expf(sb[s] - gm) * inv;
  }
}

extern "C" void kernel_launch(void* const* d_in, const int* in_sizes, int n_in,
                              void* d_out, int out_size, void* d_ws, size_t ws_size,
                              hipStream_t stream) {
  const float* position = (const float*)d_in[0];
  const float* options  = (const float*)d_in[1];
  const float* W1 = (const float*)d_in[2];
  const float* b1 = (const float*)d_in[3];
  const float* W2 = (const float*)d_in[4];
  const float* b2 = (const float*)d_in[5];
  const float* V  = (const float*)d_in[6];
  const float* bv = (const float*)d_in[7];

  float* out = (float*)d_out;
  float* ctx_out = out;              // [32,256]
  float* wgt_out = out + BB * DD;    // [32,4096]

  char* ws = (char*)d_ws;
  float* posb         = (float*)ws;                          // 32 KB
  unsigned short* w2t = (unsigned short*)(ws + 32 * 1024);   // 128 KB
  float* scores       = (float*)(ws + 160 * 1024);           // 512 KB
  float* part         = (float*)(ws + 672 * 1024);           // 2 MB
  float2* ml          = (float2*)(ws + 672 * 1024 + 2 * 1024 * 1024); // 16 KB

  k_posproj<<<BB, 256, 0, stream>>>(position, W1, b1, b2, posb);
  k_w2t<<<dim3(16, 16), 256, 0, stream>>>(W2, w2t);
  k_score_ctx<<<dim3(SS / 64, BB), 256, 0, stream>>>(options, w2t, posb, V, bv,
                                                     scores, part, ml);
  k_final<<<BB, 256, 0, stream>>>(scores, part, ml, ctx_out, wgt_out);
}